// Round 2
// baseline (200.005 us; speedup 1.0000x reference)
//
#include <hip/hip_runtime.h>

// Problem constants
#define H   16
#define E   300
#define D   768
#define HD  48
#define NN  4
#define QL  64
#define KL  64
#define NH  (NN*H)        // 64

// Workspace float offsets
#define OFF_PP 0                          // Ppart[4][384][768]
#define OFF_PF 1179648                    // Pf[384][768]  rows: 0..255 Q, 256..319 K, 320..383 V
#define OFF_A  1474560                    // A[nh=64][e=300][q=64]
#define OFF_B  2703360                    // B[nh=64][k=64][q=64]
#define OFF_SP 2965504                    // Sp[cg=4][nh=64][q=64][k=64]
// end = 4,014,080 floats = 16.1 MB

// ---------------------------------------------------------------------------
// K1: QKV projection, splitK=4.  Block tile: 64 rows x 64 cols, K-chunk 192.
// wave w handles 16 rows; lane = col.  X rows via wave-uniform s_load (SGPR),
// W staged transposed in LDS, read as ds_read_b128 per 4 dk.
// grid (6 rowblocks, 12 colblocks, 4 ksplit) = 288 blocks.
// ---------------------------------------------------------------------------
__global__ __launch_bounds__(256) void proj_kernel(
    const float* __restrict__ qin, const float* __restrict__ kin, const float* __restrict__ vin,
    const float* __restrict__ Wq, const float* __restrict__ Wk, const float* __restrict__ Wv,
    float* __restrict__ ws)
{
    const int rowblk = blockIdx.x;            // 0..5
    const int col0   = blockIdx.y * 64;       // 0..704
    const int ks     = blockIdx.z;            // 0..3
    const int kbase  = ks * 192;

    const float *X, *W; int xrow0;
    if (rowblk < 4)       { X = qin; W = Wq; xrow0 = rowblk * 64; }
    else if (rowblk == 4) { X = kin; W = Wk; xrow0 = 0; }
    else                  { X = vin; W = Wv; xrow0 = 0; }
    const int prow0 = rowblk * 64;

    __shared__ float WsT[64][68];             // [col][dk], stride 68 -> 4-way (cheap)

    const int tid  = threadIdx.x;
    const int lane = tid & 63;
    const int w    = __builtin_amdgcn_readfirstlane(tid >> 6);   // wave-uniform!

    float acc[16];
    #pragma unroll
    for (int i = 0; i < 16; i++) acc[i] = 0.f;

    for (int kk = 0; kk < 192; kk += 64) {
        // stage W tile transposed: 64 dk x 64 cols
        #pragma unroll
        for (int it = 0; it < 16; it++) {
            const int dk = (tid >> 6) + it * 4;
            const int c  = tid & 63;
            WsT[c][dk] = W[(kbase + kk + dk) * D + col0 + c];
        }
        __syncthreads();
        const float* xw = X + (xrow0 + w * 16) * D + kbase + kk;   // uniform
        #pragma unroll
        for (int d4 = 0; d4 < 16; d4++) {
            const float4 wv = *(const float4*)&WsT[lane][d4 * 4];
            #pragma unroll
            for (int i = 0; i < 16; i++) {
                const float4 xv = *(const float4*)(xw + i * D + d4 * 4);  // s_load
                acc[i] = fmaf(xv.x, wv.x, fmaf(xv.y, wv.y,
                         fmaf(xv.z, wv.z, fmaf(xv.w, wv.w, acc[i]))));
            }
        }
        __syncthreads();
    }
    float* P = ws + OFF_PP + ks * (384 * D);
    #pragma unroll
    for (int i = 0; i < 16; i++)
        P[(prow0 + w * 16 + i) * D + col0 + lane] = acc[i];
}

// ---------------------------------------------------------------------------
// K2: reduce splitK partials + bias -> Pf.  grid 288 x 256, 4 floats/thread.
// ---------------------------------------------------------------------------
__global__ __launch_bounds__(256) void reduce_kernel(
    const float* __restrict__ bq, const float* __restrict__ bk, const float* __restrict__ bv,
    float* __restrict__ ws)
{
    const int idx = (blockIdx.x * 256 + threadIdx.x) * 4;   // < 294912
    const float* PP = ws + OFF_PP;
    float4 v = *(const float4*)(PP + idx);
    #pragma unroll
    for (int c = 1; c < 4; c++) {
        const float4 p = *(const float4*)(PP + c * (384 * D) + idx);
        v.x += p.x; v.y += p.y; v.z += p.z; v.w += p.w;
    }
    const int row = idx / D, col = idx % D;
    const float* bias = (row < 256) ? bq : (row < 320) ? bk : bv;
    const float4 b = *(const float4*)(bias + col);
    v.x += b.x; v.y += b.y; v.z += b.z; v.w += b.w;
    *(float4*)(ws + OFF_PF + idx) = v;
}

// ---------------------------------------------------------------------------
// K3: A[nh][e][q] = (mem_e . Q_q),  B[nh][k][q] = (K_k . Q_q).
// Combined rows 0..299 = memory e, 300..363 = K k.  lane = q; wave = 16 rows.
// Row-side via wave-uniform s_load; Q staged in LDS (b128 per 4d).
// grid (64 nh, 6 rowgroups of 64).
// ---------------------------------------------------------------------------
__global__ __launch_bounds__(256) void ab_kernel(
    const float* __restrict__ memo, float* __restrict__ ws)
{
    const int nh = blockIdx.x;
    const int n = nh >> 4, h = nh & 15;
    const int rg = blockIdx.y;
    const float* Pf = ws + OFF_PF;
    float* A = ws + OFF_A;
    float* B = ws + OFF_B;

    __shared__ float Qs[64][52];   // stride 52: b128-aligned, 4-way conflict (cheap)

    const int tid  = threadIdx.x;
    const int lane = tid & 63;
    const int w    = __builtin_amdgcn_readfirstlane(tid >> 6);

    for (int l = tid; l < 64 * HD; l += 256) {
        const int q = l / HD, d = l % HD;
        Qs[q][d] = Pf[(n * QL + q) * D + h * HD + d];
    }
    __syncthreads();

    const int r0 = rg * 64 + w * 16;
    float acc[16];
    #pragma unroll
    for (int i = 0; i < 16; i++) acc[i] = 0.f;

    #pragma unroll
    for (int d4 = 0; d4 < 12; d4++) {
        const float4 qv = *(const float4*)&Qs[lane][d4 * 4];
        #pragma unroll
        for (int i = 0; i < 16; i++) {
            const int r = r0 + i;
            const float* rp = (r < E) ? (memo + r * D + h * HD)
                                      : (Pf + (256 + (r - E)) * D + h * HD);
            const float4 rv = *(const float4*)(rp + d4 * 4);      // s_load
            acc[i] = fmaf(rv.x, qv.x, fmaf(rv.y, qv.y,
                     fmaf(rv.z, qv.z, fmaf(rv.w, qv.w, acc[i]))));
        }
    }
    #pragma unroll
    for (int i = 0; i < 16; i++) {
        const int r = r0 + i;
        if (r < E)              A[(nh * E + r) * QL + lane] = acc[i];
        else if (r < E + KL)    B[(nh * KL + (r - E)) * QL + lane] = acc[i];
    }
}

// ---------------------------------------------------------------------------
// K4: fused core.  wave = (nh, e-chunk of 19), lane = k, all 64 q in regs.
//   m[q] = relu(sA[q] + b[q]);  p = sum_q m;  s[q] += m[q]*p
// A row via wave-uniform s_load (SGPRs) — no LDS, no shuffles in the loop.
// Block = 4 waves = 4 chunks; LDS block-reduce -> Sp[cg][nh][q][k].
// grid (64 nh, 4 cgroups) = 256 blocks = exactly 1/CU.
// ---------------------------------------------------------------------------
__global__ __launch_bounds__(256, 1) void main_kernel(float* __restrict__ ws)
{
    const int nh = blockIdx.x;
    const int cg = blockIdx.y;
    const int tid  = threadIdx.x;
    const int lane = tid & 63;                                   // k
    const int w    = __builtin_amdgcn_readfirstlane(tid >> 6);
    const int chunk = cg * 4 + w;                                // 0..15
    const int e0 = chunk * 19;
    const int e1 = (e0 + 19 < E) ? e0 + 19 : E;

    const float* Bp = ws + OFF_B + (nh * KL + lane) * QL;
    float b[64];
    #pragma unroll
    for (int j = 0; j < 16; j++)
        *(float4*)&b[j * 4] = *(const float4*)(Bp + j * 4);

    float s[64];
    #pragma unroll
    for (int j = 0; j < 64; j++) s[j] = 0.f;

    const float* Ab = ws + OFF_A + nh * (E * QL);                // uniform
    for (int e = e0; e < e1; e++) {
        const float* ar = Ab + e * QL;                           // uniform -> s_load
        float m[64];
        #pragma unroll
        for (int j = 0; j < 64; j++)
            m[j] = fmaxf(ar[j] + b[j], 0.f);
        float p0 = 0.f, p1 = 0.f, p2 = 0.f, p3 = 0.f;
        #pragma unroll
        for (int j = 0; j < 16; j++) {
            p0 += m[j * 4 + 0]; p1 += m[j * 4 + 1];
            p2 += m[j * 4 + 2]; p3 += m[j * 4 + 3];
        }
        const float p = (p0 + p1) + (p2 + p3);
        #pragma unroll
        for (int j = 0; j < 64; j++)
            s[j] += m[j] * p;
    }

    __shared__ float S_l[4][64][64];     // [wave][q][k] — writes lane-consecutive
    #pragma unroll
    for (int q = 0; q < 64; q++) S_l[w][q][lane] = s[q];
    __syncthreads();

    // block-reduce 4 chunks, write Sp[cg][nh][q][k] coalesced
    float* Sp = ws + OFF_SP + (cg * NH + nh) * (QL * KL);
    const int k = tid & 63;
    const int qs = tid >> 6;
    #pragma unroll
    for (int ii = 0; ii < 16; ii++) {
        const int q = qs * 16 + ii;
        const float v = S_l[0][q][k] + S_l[1][q][k] + S_l[2][q][k] + S_l[3][q][k];
        Sp[q * KL + k] = v;
    }
}

// ---------------------------------------------------------------------------
// K5: S = sum of 4 cgroups;  out[n,q,h,d] = sum_k S[q,k] * V[k,h,d]
// grid (64 nh, 4 q-quarters), 256 threads, 3 d per thread.
// ---------------------------------------------------------------------------
__global__ __launch_bounds__(256) void out_kernel(
    const float* __restrict__ ws_c, float* __restrict__ outp)
{
    const int nh = blockIdx.x;
    const int qq = blockIdx.y;
    const int n = nh >> 4, h = nh & 15;
    const int q0 = qq * 16;
    const float* Sp = ws_c + OFF_SP;
    const float* Pf = ws_c + OFF_PF;

    __shared__ float S_l[16][64];
    __shared__ float V_l[64][HD + 1];

    const int tid = threadIdx.x;
    for (int l = tid; l < 16 * 64; l += 256) {
        const int qi = l >> 6, k = l & 63;
        float sum = 0.f;
        #pragma unroll
        for (int c = 0; c < 4; c++)
            sum += Sp[((c * NH + nh) * QL + q0 + qi) * KL + k];
        S_l[qi][k] = sum;
    }
    for (int l = tid; l < KL * HD; l += 256) {
        const int k = l / HD, d = l % HD;
        V_l[k][d] = Pf[(320 + k) * D + h * HD + d];
    }
    __syncthreads();

    const int qi = tid >> 4;          // 0..15
    const int d0 = (tid & 15) * 3;    // 0..45
    float a0 = 0.f, a1 = 0.f, a2 = 0.f;
    #pragma unroll 8
    for (int k = 0; k < KL; k++) {
        const float sv = S_l[qi][k];
        a0 += sv * V_l[k][d0 + 0];
        a1 += sv * V_l[k][d0 + 1];
        a2 += sv * V_l[k][d0 + 2];
    }
    float* orow = outp + (n * QL + q0 + qi) * D + h * HD + d0;
    orow[0] = a0; orow[1] = a1; orow[2] = a2;
}

// ---------------------------------------------------------------------------
extern "C" void kernel_launch(void* const* d_in, const int* in_sizes, int n_in,
                              void* d_out, int out_size, void* d_ws, size_t ws_size,
                              hipStream_t stream)
{
    const float* q    = (const float*)d_in[0];
    const float* k    = (const float*)d_in[1];
    const float* v    = (const float*)d_in[2];
    const float* Wq   = (const float*)d_in[3];
    const float* bq   = (const float*)d_in[4];
    const float* Wk   = (const float*)d_in[5];
    const float* bk   = (const float*)d_in[6];
    const float* Wv   = (const float*)d_in[7];
    const float* bv   = (const float*)d_in[8];
    const float* memo = (const float*)d_in[9];
    float* ws   = (float*)d_ws;
    float* outp = (float*)d_out;

    hipLaunchKernelGGL(proj_kernel, dim3(6, 12, 4), dim3(256), 0, stream,
                       q, k, v, Wq, Wk, Wv, ws);
    hipLaunchKernelGGL(reduce_kernel, dim3(288), dim3(256), 0, stream, bq, bk, bv, ws);
    hipLaunchKernelGGL(ab_kernel, dim3(64, 6), dim3(256), 0, stream, memo, ws);
    hipLaunchKernelGGL(main_kernel, dim3(64, 4), dim3(256), 0, stream, ws);
    hipLaunchKernelGGL(out_kernel, dim3(64, 4), dim3(256), 0, stream, ws, outp);
}

// Round 3
// 124.537 us; speedup vs baseline: 1.6060x; 1.6060x over previous
//
#include <hip/hip_runtime.h>

// Problem constants
#define H   16
#define E   300
#define D   768
#define HD  48
#define QL  64
#define KL  64
#define NH  64          // n(4) * h(16)
#define ROWS 384        // 256 Q rows + 64 K + 64 V
#define SPLITK 12
#define NCH 16          // e-chunk partial count for main

// Workspace float offsets
#define OFF_PP 0                              // Ppart[12][384][768]
#define OFF_PF (SPLITK*ROWS*D)                // 3,538,944  Pf[384][768]
#define OFF_A  (OFF_PF + ROWS*D)              // 3,833,856  A[nh][e][q]
#define OFF_B  (OFF_A + NH*E*QL)              // 5,062,656  B[nh][k][q]
#define OFF_SP (OFF_B + NH*KL*QL)             // 5,324,800  Sp[16][nh][q][k]
// end = 9,519,104 floats = 38.1 MB

// ---------------------------------------------------------------------------
// K1: QKV projection.  BM=128, BN=128, BK=32, splitK=12 (K-chunk 64).
// grid (3 rowblk, 6 colblk, 12 ks) = 216 blocks, 256 thr, 8x8 microtile.
// All operand reuse through LDS with ds_read_b128.  Rowblk 2 mixes K/V rows,
// so two W tiles (one per 64-row half) are staged; half index is wave-uniform.
// ---------------------------------------------------------------------------
__global__ __launch_bounds__(256, 1) void proj_kernel(
    const float* __restrict__ qin, const float* __restrict__ kin, const float* __restrict__ vin,
    const float* __restrict__ Wq, const float* __restrict__ Wk, const float* __restrict__ Wv,
    float* __restrict__ ws)
{
    const int rowblk = blockIdx.x;            // 0..2
    const int col0   = blockIdx.y * 128;      // 0..640
    const int ks     = blockIdx.z;            // 0..11
    const int kbase  = ks * 64;

    // W pointer per 64-row half of this block
    const int g0 = rowblk * 128;
    const float* Wlo = (g0      < 256) ? Wq : (g0      < 320) ? Wk : Wv;
    const float* Whi = (g0 + 64 < 256) ? Wq : (g0 + 64 < 320) ? Wk : Wv;

    __shared__ float XsT[32][132];            // [dk][row], 132: b128-aligned, conflict-free reads
    __shared__ float Ws2[2][32][128];         // [half][dk][col]

    const int tid = threadIdx.x;
    const int r0  = (tid >> 4) * 8;           // 0..120
    const int c0  = (tid & 15) * 8;           // 0..120
    const int hw  = r0 >> 6;                  // wave-uniform W-half select

    float acc[8][8];
    #pragma unroll
    for (int i = 0; i < 8; i++)
        #pragma unroll
        for (int j = 0; j < 8; j++) acc[i][j] = 0.f;

    for (int kk2 = 0; kk2 < 64; kk2 += 32) {
        // stage X tile (128 rows x 32 dk), transposed
        #pragma unroll
        for (int it = 0; it < 4; it++) {
            const int idx = it * 256 + tid;   // 0..1023
            const int row = idx >> 3;
            const int d4  = (idx & 7) * 4;
            const int grow = rowblk * 128 + row;
            const float* src = (grow < 256) ? (qin + grow * D)
                             : (grow < 320) ? (kin + (grow - 256) * D)
                                            : (vin + (grow - 320) * D);
            const float4 xv = *(const float4*)(src + kbase + kk2 + d4);
            XsT[d4 + 0][row] = xv.x; XsT[d4 + 1][row] = xv.y;
            XsT[d4 + 2][row] = xv.z; XsT[d4 + 3][row] = xv.w;
        }
        // stage both W tiles (2 x 32 dk x 128 cols)
        #pragma unroll
        for (int it = 0; it < 8; it++) {
            const int idx  = it * 256 + tid;  // 0..2047
            const int half = idx >> 10;
            const int rem  = idx & 1023;
            const int dk   = rem >> 5;
            const int c4   = (rem & 31) * 4;
            const float* Wsel = half ? Whi : Wlo;
            *(float4*)&Ws2[half][dk][c4] =
                *(const float4*)(Wsel + (kbase + kk2 + dk) * D + col0 + c4);
        }
        __syncthreads();
        #pragma unroll
        for (int dk = 0; dk < 32; dk++) {
            const float4 x0 = *(const float4*)&XsT[dk][r0];
            const float4 x1 = *(const float4*)&XsT[dk][r0 + 4];
            const float4 w0 = *(const float4*)&Ws2[hw][dk][c0];
            const float4 w1 = *(const float4*)&Ws2[hw][dk][c0 + 4];
            const float xr[8] = {x0.x, x0.y, x0.z, x0.w, x1.x, x1.y, x1.z, x1.w};
            const float wc[8] = {w0.x, w0.y, w0.z, w0.w, w1.x, w1.y, w1.z, w1.w};
            #pragma unroll
            for (int i = 0; i < 8; i++)
                #pragma unroll
                for (int j = 0; j < 8; j++)
                    acc[i][j] = fmaf(xr[i], wc[j], acc[i][j]);
        }
        __syncthreads();
    }
    float* P = ws + OFF_PP + ks * (ROWS * D);
    #pragma unroll
    for (int i = 0; i < 8; i++) {
        float* base = P + (rowblk * 128 + r0 + i) * D + col0 + c0;
        *(float4*)(base)     = make_float4(acc[i][0], acc[i][1], acc[i][2], acc[i][3]);
        *(float4*)(base + 4) = make_float4(acc[i][4], acc[i][5], acc[i][6], acc[i][7]);
    }
}

// ---------------------------------------------------------------------------
// K2: sum 12 splitK partials + bias -> Pf.  grid 288 x 256, 4 floats/thread.
// ---------------------------------------------------------------------------
__global__ __launch_bounds__(256) void reduce_kernel(
    const float* __restrict__ bq, const float* __restrict__ bk, const float* __restrict__ bv,
    float* __restrict__ ws)
{
    const int idx = (blockIdx.x * 256 + threadIdx.x) * 4;   // < 294912
    const float* PP = ws + OFF_PP;
    float4 v = *(const float4*)(PP + idx);
    #pragma unroll
    for (int c = 1; c < SPLITK; c++) {
        const float4 p = *(const float4*)(PP + c * (ROWS * D) + idx);
        v.x += p.x; v.y += p.y; v.z += p.z; v.w += p.w;
    }
    const int row = idx / D, col = idx % D;
    const float* bias = (row < 256) ? bq : (row < 320) ? bk : bv;
    const float4 b = *(const float4*)(bias + col);
    v.x += b.x; v.y += b.y; v.z += b.z; v.w += b.w;
    *(float4*)(ws + OFF_PF + idx) = v;
}

// ---------------------------------------------------------------------------
// K3: A[nh][e][q] = mem_e . Q_q ; B[nh][k][q] = K_k . Q_q.
// Combined rows: 0..299 memory, 300..363 K.  Block: (nh, rowgroup of 128).
// Transposed LDS tiles, 8x4 microtile, b128 reads.  grid (64, 3) = 192.
// ---------------------------------------------------------------------------
__global__ __launch_bounds__(256) void ab_kernel(
    const float* __restrict__ memo, float* __restrict__ ws)
{
    const int nh = blockIdx.x;
    const int rg = blockIdx.y;                // 0..2
    const int n = nh >> 4, h = nh & 15;
    const float* Pf = ws + OFF_PF;
    float* A = ws + OFF_A;
    float* B = ws + OFF_B;

    __shared__ float RsT[48][132];            // [d][row]
    __shared__ float QsT[48][68];             // [d][q]

    const int tid = threadIdx.x;
    #pragma unroll
    for (int it = 0; it < 6; it++) {          // stage 128 rows x 48 d, transposed
        const int idx = it * 256 + tid;       // 0..1535
        const int row = idx / 12;
        const int d4  = (idx % 12) * 4;
        const int rr = rg * 128 + row;
        float4 rv = make_float4(0.f, 0.f, 0.f, 0.f);
        if (rr < E)            rv = *(const float4*)(memo + rr * D + h * HD + d4);
        else if (rr < E + KL)  rv = *(const float4*)(Pf + (256 + rr - E) * D + h * HD + d4);
        RsT[d4 + 0][row] = rv.x; RsT[d4 + 1][row] = rv.y;
        RsT[d4 + 2][row] = rv.z; RsT[d4 + 3][row] = rv.w;
    }
    #pragma unroll
    for (int it = 0; it < 3; it++) {          // stage Q slice 64 q x 48 d, transposed
        const int idx = it * 256 + tid;       // 0..767
        const int q  = idx / 12;
        const int d4 = (idx % 12) * 4;
        const float4 qv = *(const float4*)(Pf + (n * QL + q) * D + h * HD + d4);
        QsT[d4 + 0][q] = qv.x; QsT[d4 + 1][q] = qv.y;
        QsT[d4 + 2][q] = qv.z; QsT[d4 + 3][q] = qv.w;
    }
    __syncthreads();

    const int r0 = (tid >> 4) * 8;            // 0..120
    const int q0 = (tid & 15) * 4;            // 0..60
    float acc[8][4];
    #pragma unroll
    for (int i = 0; i < 8; i++)
        #pragma unroll
        for (int j = 0; j < 4; j++) acc[i][j] = 0.f;

    #pragma unroll 4
    for (int d = 0; d < HD; d++) {
        const float4 rf0 = *(const float4*)&RsT[d][r0];
        const float4 rf1 = *(const float4*)&RsT[d][r0 + 4];
        const float4 qf  = *(const float4*)&QsT[d][q0];
        const float rr8[8] = {rf0.x, rf0.y, rf0.z, rf0.w, rf1.x, rf1.y, rf1.z, rf1.w};
        const float qq4[4] = {qf.x, qf.y, qf.z, qf.w};
        #pragma unroll
        for (int i = 0; i < 8; i++)
            #pragma unroll
            for (int j = 0; j < 4; j++)
                acc[i][j] = fmaf(rr8[i], qq4[j], acc[i][j]);
    }
    #pragma unroll
    for (int i = 0; i < 8; i++) {
        const int rr = rg * 128 + r0 + i;
        const float4 av = make_float4(acc[i][0], acc[i][1], acc[i][2], acc[i][3]);
        if (rr < E)            *(float4*)(A + (nh * E + rr) * QL + q0) = av;
        else if (rr < E + KL)  *(float4*)(B + (nh * KL + (rr - E)) * QL + q0) = av;
    }
}

// ---------------------------------------------------------------------------
// K4: fused core.  Block = (nh, cg of 75 e); wave w owns e-chunk of 19.
// lane = k; all 64 q in registers.  A rows broadcast from LDS (b128, same
// address all lanes -> no conflict).  B staged in LDS once per block.
//   m[q] = relu(A[e][q] + b[q]); p = sum_q m; s[q] += m[q]*p
// Each wave writes its own partial: Sp[ch=cg*4+w][nh][q][k].  grid (64,4).
// ---------------------------------------------------------------------------
__global__ __launch_bounds__(256, 1) void main_kernel(float* __restrict__ ws)
{
    const int nh = blockIdx.x;
    const int cg = blockIdx.y;                // 0..3
    const int tid = threadIdx.x;
    const int lane = tid & 63;                // k
    const int w = tid >> 6;                   // 0..3

    __shared__ float As[75 * 64];             // 19.2 KB, A e-chunk
    __shared__ float Bs[64][68];              // 17.4 KB (68: b128-aligned rows)

    const float* Ag = ws + OFF_A + (nh * E + cg * 75) * QL;
    for (int idx = tid; idx < 1200; idx += 256)
        *(float4*)&As[idx * 4] = *(const float4*)(Ag + idx * 4);
    const float* Bg = ws + OFF_B + nh * (KL * QL);
    #pragma unroll
    for (int it = 0; it < 4; it++) {
        const int idx = it * 256 + tid;       // 0..1023
        const int k  = idx >> 4;
        const int q4 = (idx & 15) * 4;
        *(float4*)&Bs[k][q4] = *(const float4*)(Bg + idx * 4);
    }
    __syncthreads();

    float b[64];
    #pragma unroll
    for (int j = 0; j < 16; j++)
        *(float4*)&b[j * 4] = *(const float4*)&Bs[lane][j * 4];

    float s[64];
    #pragma unroll
    for (int j = 0; j < 64; j++) s[j] = 0.f;

    const int eBeg = w * 19;
    const int eEnd = (eBeg + 19 < 75) ? eBeg + 19 : 75;
    for (int e = eBeg; e < eEnd; e++) {
        float m[64];
        #pragma unroll
        for (int j4 = 0; j4 < 16; j4++) {
            const float4 a = *(const float4*)&As[e * 64 + j4 * 4];  // broadcast
            m[j4 * 4 + 0] = fmaxf(a.x + b[j4 * 4 + 0], 0.f);
            m[j4 * 4 + 1] = fmaxf(a.y + b[j4 * 4 + 1], 0.f);
            m[j4 * 4 + 2] = fmaxf(a.z + b[j4 * 4 + 2], 0.f);
            m[j4 * 4 + 3] = fmaxf(a.w + b[j4 * 4 + 3], 0.f);
        }
        float p0 = 0.f, p1 = 0.f, p2 = 0.f, p3 = 0.f;
        #pragma unroll
        for (int j4 = 0; j4 < 16; j4++) {
            p0 += m[j4 * 4 + 0]; p1 += m[j4 * 4 + 1];
            p2 += m[j4 * 4 + 2]; p3 += m[j4 * 4 + 3];
        }
        const float p = (p0 + p1) + (p2 + p3);
        #pragma unroll
        for (int j = 0; j < 64; j++)
            s[j] = fmaf(m[j], p, s[j]);
    }

    float* Sp = ws + OFF_SP + (((cg * 4 + w) * NH + nh) * QL) * KL;
    #pragma unroll
    for (int q = 0; q < 64; q++)
        Sp[q * KL + lane] = s[q];
}

// ---------------------------------------------------------------------------
// K5: S = sum of 16 partials;  out[n,q,h,d] = sum_k S[q,k] * V[k,h,d]
// grid (64 nh, 4 q-quarters), 256 thr; thread = (qi, d-group of 4), b128 V.
// ---------------------------------------------------------------------------
__global__ __launch_bounds__(256) void out_kernel(
    const float* __restrict__ ws_c, float* __restrict__ outp)
{
    const int nh = blockIdx.x;
    const int qq = blockIdx.y;
    const int n = nh >> 4, h = nh & 15;
    const int q0 = qq * 16;
    const float* Sp = ws_c + OFF_SP;
    const float* Pf = ws_c + OFF_PF;

    __shared__ float S_l[16][64];
    __shared__ float V_l[64][52];             // 52: b128-aligned rows

    const int tid = threadIdx.x;
    #pragma unroll
    for (int it = 0; it < 4; it++) {          // sum 16 partials
        const int idx = it * 256 + tid;       // 0..1023
        const int qi = idx >> 6, k = idx & 63;
        float sum = 0.f;
        #pragma unroll
        for (int c = 0; c < NCH; c++)
            sum += Sp[((c * NH + nh) * QL + q0 + qi) * KL + k];
        S_l[qi][k] = sum;
    }
    #pragma unroll
    for (int it = 0; it < 3; it++) {          // stage V slice
        const int idx = it * 256 + tid;       // 0..767
        const int k  = idx / 12;
        const int d4 = (idx % 12) * 4;
        *(float4*)&V_l[k][d4] = *(const float4*)(Pf + (320 + k) * D + h * HD + d4);
    }
    __syncthreads();

    const int qi = tid >> 4;                  // 0..15
    const int dg = tid & 15;                  // 0..15, 12 active
    if (dg < 12) {
        float a0 = 0.f, a1 = 0.f, a2 = 0.f, a3 = 0.f;
        #pragma unroll 8
        for (int k = 0; k < KL; k++) {
            const float sv = S_l[qi][k];
            const float4 vf = *(const float4*)&V_l[k][dg * 4];
            a0 = fmaf(sv, vf.x, a0); a1 = fmaf(sv, vf.y, a1);
            a2 = fmaf(sv, vf.z, a2); a3 = fmaf(sv, vf.w, a3);
        }
        *(float4*)(outp + (n * QL + q0 + qi) * D + h * HD + dg * 4) =
            make_float4(a0, a1, a2, a3);
    }
}

// ---------------------------------------------------------------------------
extern "C" void kernel_launch(void* const* d_in, const int* in_sizes, int n_in,
                              void* d_out, int out_size, void* d_ws, size_t ws_size,
                              hipStream_t stream)
{
    const float* q    = (const float*)d_in[0];
    const float* k    = (const float*)d_in[1];
    const float* v    = (const float*)d_in[2];
    const float* Wq   = (const float*)d_in[3];
    const float* bq   = (const float*)d_in[4];
    const float* Wk   = (const float*)d_in[5];
    const float* bk   = (const float*)d_in[6];
    const float* Wv   = (const float*)d_in[7];
    const float* bv   = (const float*)d_in[8];
    const float* memo = (const float*)d_in[9];
    float* ws   = (float*)d_ws;
    float* outp = (float*)d_out;

    hipLaunchKernelGGL(proj_kernel, dim3(3, 6, 12), dim3(256), 0, stream,
                       q, k, v, Wq, Wk, Wv, ws);
    hipLaunchKernelGGL(reduce_kernel, dim3(288), dim3(256), 0, stream, bq, bk, bv, ws);
    hipLaunchKernelGGL(ab_kernel, dim3(64, 3), dim3(256), 0, stream, memo, ws);
    hipLaunchKernelGGL(main_kernel, dim3(64, 4), dim3(256), 0, stream, ws);
    hipLaunchKernelGGL(out_kernel, dim3(64, 4), dim3(256), 0, stream, ws, outp);
}